// Round 7
// baseline (438.751 us; speedup 1.0000x reference)
//
#include <hip/hip_runtime.h>
#include <hip/hip_bf16.h>
#include <stdint.h>

namespace {

constexpr int Bx = 4, Tx = 2048, Cx = 1024, Hx = 16, Dx = 64;
constexpr int Mx = Bx * Tx;  // 8192

typedef __attribute__((ext_vector_type(8))) short bf16x8;
typedef __attribute__((ext_vector_type(4))) float f32x4;
typedef __attribute__((ext_vector_type(16))) float f32x16;
typedef __attribute__((ext_vector_type(2))) unsigned int u32x2;

__device__ __forceinline__ float b2f(unsigned short u) {
  unsigned int v = ((unsigned int)u) << 16;
  return __builtin_bit_cast(float, v);
}
__device__ __forceinline__ unsigned short f2b(float f) {
  unsigned int v = __builtin_bit_cast(unsigned int, f);
  v += 0x7fffu + ((v >> 16) & 1u);
  return (unsigned short)(v >> 16);
}
__device__ __forceinline__ uint32_t pkbf(float a, float b) {
  __hip_bfloat162 h = __float22bfloat162_rn(float2{a, b});
  uint32_t r;
  __builtin_memcpy(&r, &h, 4);  // __hip_bfloat162 not trivially copyable -> no bit_cast
  return r;
}
// permlane32_swap via builtin (compiler handles VALU->permlane hazards):
//   a_new[i] = i<32 ? a[i] : b[i-32];  b_new[i] = i<32 ? a[i+32] : b[i]
__device__ __forceinline__ void pl32swap(uint32_t& a, uint32_t& b) {
  u32x2 r = __builtin_amdgcn_permlane32_swap(a, b, false, false);
  a = r[0];
  b = r[1];
}
__device__ __forceinline__ float xhalf_max(float x) {
  uint32_t a = __builtin_bit_cast(uint32_t, x), b = a;
  pl32swap(a, b);
  return fmaxf(__builtin_bit_cast(float, a), __builtin_bit_cast(float, b));
}
__device__ __forceinline__ float xhalf_sum(float x) {
  uint32_t a = __builtin_bit_cast(uint32_t, x), b = a;
  pl32swap(a, b);
  return __builtin_bit_cast(float, a) + __builtin_bit_cast(float, b);
}

#define GLD16(g, lp) __builtin_amdgcn_global_load_lds(                     \
    (__attribute__((address_space(1))) void*)(g),                          \
    (__attribute__((address_space(3))) void*)(lp), 16, 0, 0)

// ---------------- convert fp32 -> bf16 (vectorized) ----------------
__global__ void ca_cvt(const float* __restrict__ src, unsigned short* __restrict__ dst, int n4) {
  int i = blockIdx.x * blockDim.x + threadIdx.x;
  int stride = gridDim.x * blockDim.x;
  for (; i < n4; i += stride) {
    float4 f = ((const float4*)src)[i];
    ushort4 o;
    o.x = f2b(f.x); o.y = f2b(f.y); o.z = f2b(f.z); o.w = f2b(f.w);
    ((ushort4*)dst)[i] = o;
  }
}

// ---------------- W (K x N) -> Wt (N x K) bf16 ----------------
__global__ void ca_wt(const float* __restrict__ W, unsigned short* __restrict__ Wt) {
  __shared__ float tile[32][33];
  int n0 = blockIdx.x * 32, k0 = blockIdx.y * 32;
  int j = threadIdx.x & 31, i = threadIdx.x >> 5;  // i in 0..7
#pragma unroll
  for (int r = 0; r < 4; ++r)
    tile[i + 8 * r][j] = W[(size_t)(k0 + i + 8 * r) * Cx + n0 + j];
  __syncthreads();
#pragma unroll
  for (int r = 0; r < 4; ++r)
    Wt[(size_t)(n0 + i + 8 * r) * Cx + k0 + j] = f2b(tile[j][i + 8 * r]);
}

// ---------------- RoPE cos/sin table ----------------
__global__ void ca_rtab(float* __restrict__ ct, float* __restrict__ st) {
  int idx = blockIdx.x * blockDim.x + threadIdx.x;  // < Tx*32
  int t = idx >> 5, i = idx & 31;
  float fr = expf((float)i * -0.29710775393471563f);  // -ln(10000)/31
  float a = (float)t * fr;
  ct[idx] = cosf(a);
  st[idx] = sinf(a);
}

// ---------------- GEMM: A (MxK bf16) x Bt (NxK bf16) + bias ----------------
// m97 structure: 128x128 tile, BK=32, global_load_lds width-16, 2-barrier loop.
template <int MODE>
__global__ __launch_bounds__(256) void ca_gemm(
    const unsigned short* __restrict__ A, const unsigned short* __restrict__ Bt,
    const float* __restrict__ b0, const float* __restrict__ b1, const float* __restrict__ b2,
    void* __restrict__ out, int M, int N, int K) {
  __shared__ __align__(16) unsigned short Al[128 * 32];
  __shared__ __align__(16) unsigned short Bl[128 * 32];
  int tid = threadIdx.x;
  int w = tid >> 6, l = tid & 63;
  int m0 = blockIdx.x * 128, n0 = blockIdx.y * 128;
  int wm = (w >> 1) * 64, wn = (w & 1) * 64;
  f32x4 acc[4][4] = {};

  int lr = l & 15, lk8 = (l >> 4) * 8;
  int srow = w * 32 + (l >> 2), scol = (l & 3) * 8;
  const unsigned short* ga0 = A + (size_t)(m0 + srow) * K + scol;
  const unsigned short* gb0 = Bt + (size_t)(n0 + srow) * K + scol;
  unsigned short* la = &Al[w * 1024];
  unsigned short* lb = &Bl[w * 1024];
  int nk = K / 32;
  for (int kt = 0; kt < nk; ++kt) {
    const unsigned short* ga = ga0 + kt * 32;
    const unsigned short* gb = gb0 + kt * 32;
    GLD16(ga, la);
    GLD16(ga + (size_t)16 * K, la + 512);
    GLD16(gb, lb);
    GLD16(gb + (size_t)16 * K, lb + 512);
    __syncthreads();
    bf16x8 af[4], bfr[4];
#pragma unroll
    for (int mi = 0; mi < 4; ++mi) af[mi] = *(const bf16x8*)&Al[(wm + mi * 16 + lr) * 32 + lk8];
#pragma unroll
    for (int ni = 0; ni < 4; ++ni) bfr[ni] = *(const bf16x8*)&Bl[(wn + ni * 16 + lr) * 32 + lk8];
#pragma unroll
    for (int mi = 0; mi < 4; ++mi)
#pragma unroll
      for (int ni = 0; ni < 4; ++ni)
        acc[mi][ni] = __builtin_amdgcn_mfma_f32_16x16x32_bf16(af[mi], bfr[ni], acc[mi][ni], 0, 0, 0);
    __syncthreads();
  }

  int lq4 = (l >> 4) * 4;
  if (MODE == 0) {
    int which = n0 >> 10;
    int nb = n0 & 1023;
    const float* bias = which == 0 ? b0 : (which == 1 ? b1 : b2);
    unsigned short* o = (unsigned short*)out + (size_t)which * M * 1024;
#pragma unroll
    for (int mi = 0; mi < 4; ++mi)
#pragma unroll
      for (int ni = 0; ni < 4; ++ni) {
        int ncol = nb + wn + ni * 16 + lr;
        float bv = bias[ncol];
#pragma unroll
        for (int rg = 0; rg < 4; ++rg) {
          int m = m0 + wm + mi * 16 + lq4 + rg;
          o[(size_t)m * 1024 + ncol] = f2b(acc[mi][ni][rg] + bv);
        }
      }
  } else {
    float* o = (float*)out;
#pragma unroll
    for (int mi = 0; mi < 4; ++mi)
#pragma unroll
      for (int ni = 0; ni < 4; ++ni) {
        int ncol = n0 + wn + ni * 16 + lr;
        float bv = b0[ncol];
#pragma unroll
        for (int rg = 0; rg < 4; ++rg) {
          int m = m0 + wm + mi * 16 + lq4 + rg;
          o[(size_t)m * N + ncol] = acc[mi][ni][rg] + bv;
        }
      }
  }
}

// ---------------- RoPE apply (in-place on q and k, bf16) ----------------
// Q is additionally pre-scaled by 0.125*log2(e) so attention scores come out
// of the QK^T MFMA directly in log2 domain.
__global__ void ca_rope(unsigned short* __restrict__ q, unsigned short* __restrict__ k,
                        const float* __restrict__ ct, const float* __restrict__ st) {
  constexpr float SC = 0.18033688011112042f;  // 0.125 * log2(e)
  int p = blockIdx.x * blockDim.x + threadIdx.x;  // handles 8 elems (4 pairs)
  int e = p * 8;
  int col = e & (Cx - 1);
  int t = (e >> 10) & (Tx - 1);
  int j0 = (col & (Dx - 1)) >> 1;
  float c[4], s[4];
#pragma unroll
  for (int jj = 0; jj < 4; ++jj) {
    c[jj] = ct[t * 32 + j0 + jj];
    s[jj] = st[t * 32 + j0 + jj];
  }
  {
    uint4 v = *(uint4*)&q[e];
    unsigned short* u = (unsigned short*)&v;
#pragma unroll
    for (int pr = 0; pr < 4; ++pr) {
      float xr = b2f(u[2 * pr]), xi = b2f(u[2 * pr + 1]);
      u[2 * pr] = f2b((xr * c[pr] - xi * s[pr]) * SC);
      u[2 * pr + 1] = f2b((xr * s[pr] + xi * c[pr]) * SC);
    }
    *(uint4*)&q[e] = v;
  }
  {
    uint4 v = *(uint4*)&k[e];
    unsigned short* u = (unsigned short*)&v;
#pragma unroll
    for (int pr = 0; pr < 4; ++pr) {
      float xr = b2f(u[2 * pr]), xi = b2f(u[2 * pr + 1]);
      u[2 * pr] = f2b(xr * c[pr] - xi * s[pr]);
      u[2 * pr + 1] = f2b(xr * s[pr] + xi * c[pr]);
    }
    *(uint4*)&k[e] = v;
  }
}

// ---------------- V (B,T,C) -> vT (B,H,D,T) ----------------
__global__ void ca_vt(const unsigned short* __restrict__ v, unsigned short* __restrict__ vT) {
  __shared__ __align__(16) unsigned short tl[64][72];
  int t0 = blockIdx.x * 64;
  int bh = blockIdx.y;
  int b = bh >> 4, h = bh & 15;
  int tid = threadIdx.x;
  const unsigned short* vb = v + (size_t)b * Tx * Cx + h * Dx;
#pragma unroll
  for (int it = 0; it < 2; ++it) {
    int tt = it * 32 + (tid >> 3), d0 = (tid & 7) * 8;
    uint4 x = *(const uint4*)&vb[(size_t)(t0 + tt) * Cx + d0];
    unsigned short* u = (unsigned short*)&x;
#pragma unroll
    for (int jj = 0; jj < 8; ++jj) tl[d0 + jj][tt] = u[jj];
  }
  __syncthreads();
  unsigned short* o = vT + (size_t)bh * Dx * Tx;
#pragma unroll
  for (int it = 0; it < 2; ++it) {
    int d = it * 32 + (tid >> 3), tc = (tid & 7) * 8;
    *(uint4*)&o[(size_t)d * Tx + t0 + tc] = *(const uint4*)&tl[d][tc];
  }
}

// ---------------- causal flash attention, KV-split ---------------------------
// Grid (bh=64, qt=64), 4-wave blocks. Wave w handles a contiguous quarter of
// the kv-tile range [0, qt+1) with private online-softmax state (m, l, acc);
// states merge at the end (flash combine) via LDS f32 atomics. Critical block
// shrinks 64 -> 16 serial tiles (r6 post-mortem: per-tile serial chain ~2.5k
// cyc, ~80% stall; the heavy-block tail dominated the old 1-wave layout).
__global__ __launch_bounds__(256) void ca_attn(
    const unsigned short* __restrict__ q, const unsigned short* __restrict__ k,
    const unsigned short* __restrict__ vT, unsigned short* __restrict__ y) {
  __shared__ float msh[4][32], lsh[4][32];
  __shared__ float osum[32][66];
  int tid = threadIdx.x, w = tid >> 6, l = tid & 63;
  int bh = blockIdx.x;                              // XCD = id%8 = bh%8 -> KV L2-pinned
  int qt = (int)gridDim.y - 1 - (int)blockIdx.y;    // heavy q-tiles first
  int b = bh >> 4, h = bh & 15;
  const unsigned short* qp = q + (size_t)b * Tx * Cx + h * Dx;
  const unsigned short* kp = k + (size_t)b * Tx * Cx + h * Dx;
  const unsigned short* vp = vT + (size_t)bh * Dx * Tx;
  int qbase = qt * 32;
  int lo = l & 31, hi = l >> 5;

  // zero the merge accumulator while everything else warms up
  for (int i = tid; i < 32 * 66; i += 256) (&osum[0][0])[i] = 0.f;

  bf16x8 qf[4];
  {
    const unsigned short* qr = qp + (size_t)(qbase + lo) * Cx + hi * 8;
#pragma unroll
    for (int c = 0; c < 4; ++c) qf[c] = *(const bf16x8*)(qr + c * 16);
  }

  f32x16 acc0 = {}, acc1 = {};
  float m = -__builtin_inff(), lsum = 0.f;
  int nt = qt + 1;
  int per = (nt + 3) >> 2;
  int t0 = w * per;
  int t1 = min(nt, t0 + per);

  uint4 rk[4], rv[4];
  const unsigned short* kr0 = kp + (size_t)lo * Cx + hi * 8;
  const unsigned short* vr0 = vp + (size_t)lo * Tx + hi * 8;
  auto loadK = [&](int t) {
    const unsigned short* kr = kr0 + (size_t)t * 32 * Cx;
#pragma unroll
    for (int c = 0; c < 4; ++c) rk[c] = *(const uint4*)(kr + c * 16);
  };
  auto loadV = [&](int t) {
#pragma unroll
    for (int dc = 0; dc < 2; ++dc)
#pragma unroll
      for (int kc = 0; kc < 2; ++kc)
        rv[dc * 2 + kc] = *(const uint4*)(vr0 + (size_t)dc * 32 * Tx + t * 32 + kc * 16);
  };

  if (t0 < t1) {
    loadK(t0);
    loadV(t0);
    for (int t = t0; t < t1; ++t) {
      bf16x8 kf[4], vf[4];
#pragma unroll
      for (int c = 0; c < 4; ++c) kf[c] = __builtin_bit_cast(bf16x8, rk[c]);
#pragma unroll
      for (int c = 0; c < 4; ++c) vf[c] = __builtin_bit_cast(bf16x8, rv[c]);
      if (t + 1 < t1) { loadK(t + 1); loadV(t + 1); }  // prefetch under softmax

      // QK^T: two independent 2-deep MFMA chains over D-halves (shorter
      // dependency chain), summed in VALU.
      __builtin_amdgcn_s_setprio(1);
      f32x16 sa = {}, sb = {};
      sa = __builtin_amdgcn_mfma_f32_32x32x16_bf16(kf[0], qf[0], sa, 0, 0, 0);
      sb = __builtin_amdgcn_mfma_f32_32x32x16_bf16(kf[1], qf[1], sb, 0, 0, 0);
      sa = __builtin_amdgcn_mfma_f32_32x32x16_bf16(kf[2], qf[2], sa, 0, 0, 0);
      sb = __builtin_amdgcn_mfma_f32_32x32x16_bf16(kf[3], qf[3], sb, 0, 0, 0);
      __builtin_amdgcn_s_setprio(0);

      // scores already in log2 domain (Q pre-scaled by 0.125*log2e in ca_rope)
      float tv[16];
#pragma unroll
      for (int r = 0; r < 16; ++r) tv[r] = sa[r] + sb[r];
      if (t == nt - 1) {  // diagonal tile
#pragma unroll
        for (int r = 0; r < 16; ++r) {
          int kvr = (r & 3) + 8 * (r >> 2) + 4 * hi;
          if (kvr > lo) tv[r] = -3.0e38f;
        }
      }
      // balanced max tree (fuses to v_max3)
      float mx[8];
#pragma unroll
      for (int r = 0; r < 8; ++r) mx[r] = fmaxf(tv[2 * r], tv[2 * r + 1]);
#pragma unroll
      for (int r = 0; r < 4; ++r) mx[r] = fmaxf(mx[2 * r], mx[2 * r + 1]);
      float pmax = fmaxf(fmaxf(mx[0], mx[1]), fmaxf(mx[2], mx[3]));
      pmax = xhalf_max(pmax);
      if (!__all(pmax - m <= 11.0f)) {  // defer-max (T13), log2 units
        float mn = fmaxf(m, pmax);
        float al = exp2f(m - mn);
        m = mn;
        lsum *= al;
#pragma unroll
        for (int r = 0; r < 16; ++r) { acc0[r] *= al; acc1[r] *= al; }
      }
      float p[16];
#pragma unroll
      for (int r = 0; r < 16; ++r) p[r] = exp2f(tv[r] - m);
      // balanced sum tree
      float sm[8];
#pragma unroll
      for (int r = 0; r < 8; ++r) sm[r] = p[2 * r] + p[2 * r + 1];
#pragma unroll
      for (int r = 0; r < 4; ++r) sm[r] = sm[2 * r] + sm[2 * r + 1];
      float ps = (sm[0] + sm[1]) + (sm[2] + sm[3]);
      lsum += xhalf_sum(ps);

      // pack P -> bf16 pairs; kv redistribution via 4 permlane32_swap
      uint32_t pk[8];
#pragma unroll
      for (int i = 0; i < 8; ++i) pk[i] = pkbf(p[2 * i], p[2 * i + 1]);
      pl32swap(pk[0], pk[2]);
      pl32swap(pk[1], pk[3]);
      pl32swap(pk[4], pk[6]);
      pl32swap(pk[5], pk[7]);
      uint4 xw{pk[0], pk[1], pk[2], pk[3]}, yw{pk[4], pk[5], pk[6], pk[7]};
      bf16x8 PB0 = __builtin_bit_cast(bf16x8, xw);
      bf16x8 PB1 = __builtin_bit_cast(bf16x8, yw);
      __builtin_amdgcn_s_setprio(1);
      acc0 = __builtin_amdgcn_mfma_f32_32x32x16_bf16(vf[0], PB0, acc0, 0, 0, 0);
      acc1 = __builtin_amdgcn_mfma_f32_32x32x16_bf16(vf[2], PB0, acc1, 0, 0, 0);
      acc0 = __builtin_amdgcn_mfma_f32_32x32x16_bf16(vf[1], PB1, acc0, 0, 0, 0);
      acc1 = __builtin_amdgcn_mfma_f32_32x32x16_bf16(vf[3], PB1, acc1, 0, 0, 0);
      __builtin_amdgcn_s_setprio(0);
    }
  }

  // ---- flash combine across the 4 kv-chunks ----
  if (hi == 0) { msh[w][lo] = m; lsh[w][lo] = lsum; }
  __syncthreads();
  float m0 = fmaxf(fmaxf(msh[0][lo], msh[1][lo]), fmaxf(msh[2][lo], msh[3][lo]));
  float ls = lsh[0][lo] * exp2f(msh[0][lo] - m0) + lsh[1][lo] * exp2f(msh[1][lo] - m0) +
             lsh[2][lo] * exp2f(msh[2][lo] - m0) + lsh[3][lo] * exp2f(msh[3][lo] - m0);
  float sw = exp2f(m - m0) * __builtin_amdgcn_rcpf(ls);  // this wave's scale
  if (t0 < t1) {
#pragma unroll
    for (int dc = 0; dc < 2; ++dc) {
      f32x16 a = dc ? acc1 : acc0;
#pragma unroll
      for (int i = 0; i < 8; ++i) {
        int d2 = (i & 1) + 4 * (i >> 1) + 2 * hi + dc * 16;
        atomicAdd(&osum[lo][2 * d2], a[2 * i] * sw);
        atomicAdd(&osum[lo][2 * d2 + 1], a[2 * i + 1] * sw);
      }
    }
  }
  __syncthreads();

  // epilogue: osum (q x d, f32) -> bf16 coalesced row writes
  unsigned short* yp = y + (size_t)b * Tx * Cx + h * Dx;
  int qr = tid >> 3, d0 = (tid & 7) * 8;
  uint4 ov;
  ov.x = pkbf(osum[qr][d0 + 0], osum[qr][d0 + 1]);
  ov.y = pkbf(osum[qr][d0 + 2], osum[qr][d0 + 3]);
  ov.z = pkbf(osum[qr][d0 + 4], osum[qr][d0 + 5]);
  ov.w = pkbf(osum[qr][d0 + 6], osum[qr][d0 + 7]);
  *(uint4*)(yp + (size_t)(qbase + qr) * Cx + d0) = ov;
}

}  // namespace

extern "C" void kernel_launch(void* const* d_in, const int* in_sizes, int n_in,
                              void* d_out, int out_size, void* d_ws, size_t ws_size,
                              hipStream_t stream) {
  const float* x = (const float*)d_in[0];
  const float* Wq = (const float*)d_in[1];
  const float* bq = (const float*)d_in[2];
  const float* Wk = (const float*)d_in[3];
  const float* bk = (const float*)d_in[4];
  const float* Wv = (const float*)d_in[5];
  const float* bv = (const float*)d_in[6];
  const float* Wp = (const float*)d_in[7];
  const float* bp = (const float*)d_in[8];

  unsigned short* xb = (unsigned short*)d_ws;                 // 8192*1024
  unsigned short* wt = xb + (size_t)Mx * Cx;                  // 4 * 1024*1024 (WqT,WkT,WvT,WpT)
  float* ct = (float*)(wt + (size_t)4 * Cx * Cx);             // 2048*32
  float* st = ct + Tx * 32;
  unsigned short* qb = (unsigned short*)(st + Tx * 32);       // q,k,v consecutive (split3 GEMM out)
  unsigned short* kb = qb + (size_t)Mx * Cx;
  unsigned short* vb = kb + (size_t)Mx * Cx;
  unsigned short* vT = vb + (size_t)Mx * Cx;
  unsigned short* yb = vT + (size_t)Mx * Cx;

  ca_cvt<<<dim3(2048), dim3(256), 0, stream>>>(x, xb, Mx * Cx / 4);
  ca_wt<<<dim3(32, 32), dim3(256), 0, stream>>>(Wq, wt + (size_t)0 * Cx * Cx);
  ca_wt<<<dim3(32, 32), dim3(256), 0, stream>>>(Wk, wt + (size_t)1 * Cx * Cx);
  ca_wt<<<dim3(32, 32), dim3(256), 0, stream>>>(Wv, wt + (size_t)2 * Cx * Cx);
  ca_wt<<<dim3(32, 32), dim3(256), 0, stream>>>(Wp, wt + (size_t)3 * Cx * Cx);
  ca_rtab<<<dim3(Tx * 32 / 256), dim3(256), 0, stream>>>(ct, st);

  ca_gemm<0><<<dim3(64, 24), dim3(256), 0, stream>>>(xb, wt, bq, bk, bv, qb, Mx, 3072, Cx);
  ca_rope<<<dim3(Mx * Cx / 8 / 256), dim3(256), 0, stream>>>(qb, kb, ct, st);
  ca_vt<<<dim3(Tx / 64, Bx * Hx), dim3(256), 0, stream>>>(vb, vT);
  ca_attn<<<dim3(64, 64), dim3(256), 0, stream>>>(qb, kb, vT, yb);
  ca_gemm<1><<<dim3(64, 8), dim3(256), 0, stream>>>(yb, wt + (size_t)3 * Cx * Cx, bp,
                                                    nullptr, nullptr, d_out, Mx, Cx, Cx);
}

// Round 8
// 265.741 us; speedup vs baseline: 1.6510x; 1.6510x over previous
//
#include <hip/hip_runtime.h>
#include <hip/hip_bf16.h>
#include <stdint.h>

namespace {

constexpr int Bx = 4, Tx = 2048, Cx = 1024, Hx = 16, Dx = 64;
constexpr int Mx = Bx * Tx;  // 8192

typedef __attribute__((ext_vector_type(8))) short bf16x8;
typedef __attribute__((ext_vector_type(4))) float f32x4;
typedef __attribute__((ext_vector_type(16))) float f32x16;
typedef __attribute__((ext_vector_type(2))) unsigned int u32x2;

__device__ __forceinline__ float b2f(unsigned short u) {
  unsigned int v = ((unsigned int)u) << 16;
  return __builtin_bit_cast(float, v);
}
__device__ __forceinline__ unsigned short f2b(float f) {
  unsigned int v = __builtin_bit_cast(unsigned int, f);
  v += 0x7fffu + ((v >> 16) & 1u);
  return (unsigned short)(v >> 16);
}
__device__ __forceinline__ uint32_t pkbf(float a, float b) {
  __hip_bfloat162 h = __float22bfloat162_rn(float2{a, b});
  uint32_t r;
  __builtin_memcpy(&r, &h, 4);  // __hip_bfloat162 not trivially copyable -> no bit_cast
  return r;
}
// permlane32_swap via builtin (compiler handles VALU->permlane hazards):
//   a_new[i] = i<32 ? a[i] : b[i-32];  b_new[i] = i<32 ? a[i+32] : b[i]
__device__ __forceinline__ void pl32swap(uint32_t& a, uint32_t& b) {
  u32x2 r = __builtin_amdgcn_permlane32_swap(a, b, false, false);
  a = r[0];
  b = r[1];
}
__device__ __forceinline__ float xhalf_max(float x) {
  uint32_t a = __builtin_bit_cast(uint32_t, x), b = a;
  pl32swap(a, b);
  return fmaxf(__builtin_bit_cast(float, a), __builtin_bit_cast(float, b));
}
__device__ __forceinline__ float xhalf_sum(float x) {
  uint32_t a = __builtin_bit_cast(uint32_t, x), b = a;
  pl32swap(a, b);
  return __builtin_bit_cast(float, a) + __builtin_bit_cast(float, b);
}

#define GLD16(g, lp) __builtin_amdgcn_global_load_lds(                     \
    (__attribute__((address_space(1))) void*)(g),                          \
    (__attribute__((address_space(3))) void*)(lp), 16, 0, 0)

// ---------------- convert fp32 -> bf16 (vectorized) ----------------
__global__ void ca_cvt(const float* __restrict__ src, unsigned short* __restrict__ dst, int n4) {
  int i = blockIdx.x * blockDim.x + threadIdx.x;
  int stride = gridDim.x * blockDim.x;
  for (; i < n4; i += stride) {
    float4 f = ((const float4*)src)[i];
    ushort4 o;
    o.x = f2b(f.x); o.y = f2b(f.y); o.z = f2b(f.z); o.w = f2b(f.w);
    ((ushort4*)dst)[i] = o;
  }
}

// ---------------- W (K x N) -> Wt (N x K) bf16 ----------------
__global__ void ca_wt(const float* __restrict__ W, unsigned short* __restrict__ Wt) {
  __shared__ float tile[32][33];
  int n0 = blockIdx.x * 32, k0 = blockIdx.y * 32;
  int j = threadIdx.x & 31, i = threadIdx.x >> 5;  // i in 0..7
#pragma unroll
  for (int r = 0; r < 4; ++r)
    tile[i + 8 * r][j] = W[(size_t)(k0 + i + 8 * r) * Cx + n0 + j];
  __syncthreads();
#pragma unroll
  for (int r = 0; r < 4; ++r)
    Wt[(size_t)(n0 + i + 8 * r) * Cx + k0 + j] = f2b(tile[j][i + 8 * r]);
}

// ---------------- RoPE cos/sin table ----------------
__global__ void ca_rtab(float* __restrict__ ct, float* __restrict__ st) {
  int idx = blockIdx.x * blockDim.x + threadIdx.x;  // < Tx*32
  int t = idx >> 5, i = idx & 31;
  float fr = expf((float)i * -0.29710775393471563f);  // -ln(10000)/31
  float a = (float)t * fr;
  ct[idx] = cosf(a);
  st[idx] = sinf(a);
}

// ---------------- GEMM: A (MxK bf16) x Bt (NxK bf16) + bias ----------------
// m97 structure: 128x128 tile, BK=32, global_load_lds width-16, 2-barrier loop.
template <int MODE>
__global__ __launch_bounds__(256) void ca_gemm(
    const unsigned short* __restrict__ A, const unsigned short* __restrict__ Bt,
    const float* __restrict__ b0, const float* __restrict__ b1, const float* __restrict__ b2,
    void* __restrict__ out, int M, int N, int K) {
  __shared__ __align__(16) unsigned short Al[128 * 32];
  __shared__ __align__(16) unsigned short Bl[128 * 32];
  int tid = threadIdx.x;
  int w = tid >> 6, l = tid & 63;
  int m0 = blockIdx.x * 128, n0 = blockIdx.y * 128;
  int wm = (w >> 1) * 64, wn = (w & 1) * 64;
  f32x4 acc[4][4] = {};

  int lr = l & 15, lk8 = (l >> 4) * 8;
  int srow = w * 32 + (l >> 2), scol = (l & 3) * 8;
  const unsigned short* ga0 = A + (size_t)(m0 + srow) * K + scol;
  const unsigned short* gb0 = Bt + (size_t)(n0 + srow) * K + scol;
  unsigned short* la = &Al[w * 1024];
  unsigned short* lb = &Bl[w * 1024];
  int nk = K / 32;
  for (int kt = 0; kt < nk; ++kt) {
    const unsigned short* ga = ga0 + kt * 32;
    const unsigned short* gb = gb0 + kt * 32;
    GLD16(ga, la);
    GLD16(ga + (size_t)16 * K, la + 512);
    GLD16(gb, lb);
    GLD16(gb + (size_t)16 * K, lb + 512);
    __syncthreads();
    bf16x8 af[4], bfr[4];
#pragma unroll
    for (int mi = 0; mi < 4; ++mi) af[mi] = *(const bf16x8*)&Al[(wm + mi * 16 + lr) * 32 + lk8];
#pragma unroll
    for (int ni = 0; ni < 4; ++ni) bfr[ni] = *(const bf16x8*)&Bl[(wn + ni * 16 + lr) * 32 + lk8];
#pragma unroll
    for (int mi = 0; mi < 4; ++mi)
#pragma unroll
      for (int ni = 0; ni < 4; ++ni)
        acc[mi][ni] = __builtin_amdgcn_mfma_f32_16x16x32_bf16(af[mi], bfr[ni], acc[mi][ni], 0, 0, 0);
    __syncthreads();
  }

  int lq4 = (l >> 4) * 4;
  if (MODE == 0) {
    int which = n0 >> 10;
    int nb = n0 & 1023;
    const float* bias = which == 0 ? b0 : (which == 1 ? b1 : b2);
    unsigned short* o = (unsigned short*)out + (size_t)which * M * 1024;
#pragma unroll
    for (int mi = 0; mi < 4; ++mi)
#pragma unroll
      for (int ni = 0; ni < 4; ++ni) {
        int ncol = nb + wn + ni * 16 + lr;
        float bv = bias[ncol];
#pragma unroll
        for (int rg = 0; rg < 4; ++rg) {
          int m = m0 + wm + mi * 16 + lq4 + rg;
          o[(size_t)m * 1024 + ncol] = f2b(acc[mi][ni][rg] + bv);
        }
      }
  } else {
    float* o = (float*)out;
#pragma unroll
    for (int mi = 0; mi < 4; ++mi)
#pragma unroll
      for (int ni = 0; ni < 4; ++ni) {
        int ncol = n0 + wn + ni * 16 + lr;
        float bv = b0[ncol];
#pragma unroll
        for (int rg = 0; rg < 4; ++rg) {
          int m = m0 + wm + mi * 16 + lq4 + rg;
          o[(size_t)m * N + ncol] = acc[mi][ni][rg] + bv;
        }
      }
  }
}

// ---------------- RoPE apply (in-place on q and k, bf16) ----------------
// Q is additionally pre-scaled by 0.125*log2(e) so attention scores come out
// of the QK^T MFMA directly in log2 domain.
__global__ void ca_rope(unsigned short* __restrict__ q, unsigned short* __restrict__ k,
                        const float* __restrict__ ct, const float* __restrict__ st) {
  constexpr float SC = 0.18033688011112042f;  // 0.125 * log2(e)
  int p = blockIdx.x * blockDim.x + threadIdx.x;  // handles 8 elems (4 pairs)
  int e = p * 8;
  int col = e & (Cx - 1);
  int t = (e >> 10) & (Tx - 1);
  int j0 = (col & (Dx - 1)) >> 1;
  float c[4], s[4];
#pragma unroll
  for (int jj = 0; jj < 4; ++jj) {
    c[jj] = ct[t * 32 + j0 + jj];
    s[jj] = st[t * 32 + j0 + jj];
  }
  {
    uint4 v = *(uint4*)&q[e];
    unsigned short* u = (unsigned short*)&v;
#pragma unroll
    for (int pr = 0; pr < 4; ++pr) {
      float xr = b2f(u[2 * pr]), xi = b2f(u[2 * pr + 1]);
      u[2 * pr] = f2b((xr * c[pr] - xi * s[pr]) * SC);
      u[2 * pr + 1] = f2b((xr * s[pr] + xi * c[pr]) * SC);
    }
    *(uint4*)&q[e] = v;
  }
  {
    uint4 v = *(uint4*)&k[e];
    unsigned short* u = (unsigned short*)&v;
#pragma unroll
    for (int pr = 0; pr < 4; ++pr) {
      float xr = b2f(u[2 * pr]), xi = b2f(u[2 * pr + 1]);
      u[2 * pr] = f2b(xr * c[pr] - xi * s[pr]);
      u[2 * pr + 1] = f2b(xr * s[pr] + xi * c[pr]);
    }
    *(uint4*)&k[e] = v;
  }
}

// ---------------- V (B,T,C) -> vT (B,H,D,T) ----------------
__global__ void ca_vt(const unsigned short* __restrict__ v, unsigned short* __restrict__ vT) {
  __shared__ __align__(16) unsigned short tl[64][72];
  int t0 = blockIdx.x * 64;
  int bh = blockIdx.y;
  int b = bh >> 4, h = bh & 15;
  int tid = threadIdx.x;
  const unsigned short* vb = v + (size_t)b * Tx * Cx + h * Dx;
#pragma unroll
  for (int it = 0; it < 2; ++it) {
    int tt = it * 32 + (tid >> 3), d0 = (tid & 7) * 8;
    uint4 x = *(const uint4*)&vb[(size_t)(t0 + tt) * Cx + d0];
    unsigned short* u = (unsigned short*)&x;
#pragma unroll
    for (int jj = 0; jj < 8; ++jj) tl[d0 + jj][tt] = u[jj];
  }
  __syncthreads();
  unsigned short* o = vT + (size_t)bh * Dx * Tx;
#pragma unroll
  for (int it = 0; it < 2; ++it) {
    int d = it * 32 + (tid >> 3), tc = (tid & 7) * 8;
    *(uint4*)&o[(size_t)d * Tx + t0 + tc] = *(const uint4*)&tl[d][tc];
  }
}

// ---------------- causal flash attention, balanced q-tile pairs -------------
// 1-wave (64-thread) blocks. Block (bh, j) processes q-tiles j and 63-j
// SEQUENTIALLY with the exact r6 inner loop: (j+1) + (64-j) = 65 kv-tiles for
// EVERY wave -> zero load imbalance, no merge/atomics (r7 post-mortem: the
// KV-split merge regressed 2.3x; r6 post-mortem: triangular imbalance drained
// time-avg occupancy to 21% of 50% static). 2048 blocks all resident.
__global__ __launch_bounds__(64) void ca_attn(
    const unsigned short* __restrict__ q, const unsigned short* __restrict__ k,
    const unsigned short* __restrict__ vT, unsigned short* __restrict__ y) {
  __shared__ uint32_t els[32][33];
  int l = threadIdx.x & 63;
  int bh = blockIdx.x;                              // XCD = id%8 = bh%8 -> KV L2-pinned
  int jp = (int)blockIdx.y;                         // 0..31
  int b = bh >> 4, h = bh & 15;
  const unsigned short* qp = q + (size_t)b * Tx * Cx + h * Dx;
  const unsigned short* kp = k + (size_t)b * Tx * Cx + h * Dx;
  const unsigned short* vp = vT + (size_t)bh * Dx * Tx;
  int lo = l & 31, hi = l >> 5;

  const unsigned short* kr0 = kp + (size_t)lo * Cx + hi * 8;
  const unsigned short* vr0 = vp + (size_t)lo * Tx + hi * 8;

  for (int pass = 0; pass < 2; ++pass) {
    int qt = pass ? 63 - jp : jp;
    int qbase = qt * 32;

    bf16x8 qf[4];
    {
      const unsigned short* qr = qp + (size_t)(qbase + lo) * Cx + hi * 8;
#pragma unroll
      for (int c = 0; c < 4; ++c) qf[c] = *(const bf16x8*)(qr + c * 16);
    }

    f32x16 acc0 = {}, acc1 = {};
    float m = -__builtin_inff(), lsum = 0.f;
    int nt = qt + 1;

    uint4 rk[4], rv[4];
    auto loadK = [&](int t) {
      const unsigned short* kr = kr0 + (size_t)t * 32 * Cx;
#pragma unroll
      for (int c = 0; c < 4; ++c) rk[c] = *(const uint4*)(kr + c * 16);
    };
    auto loadV = [&](int t) {
#pragma unroll
      for (int dc = 0; dc < 2; ++dc)
#pragma unroll
        for (int kc = 0; kc < 2; ++kc)
          rv[dc * 2 + kc] = *(const uint4*)(vr0 + (size_t)dc * 32 * Tx + t * 32 + kc * 16);
    };
    loadK(0);
    loadV(0);

    for (int t = 0; t < nt; ++t) {
      bf16x8 kf[4], vf[4];
#pragma unroll
      for (int c = 0; c < 4; ++c) kf[c] = __builtin_bit_cast(bf16x8, rk[c]);
#pragma unroll
      for (int c = 0; c < 4; ++c) vf[c] = __builtin_bit_cast(bf16x8, rv[c]);
      if (t + 1 < nt) { loadK(t + 1); loadV(t + 1); }  // prefetch under softmax

      // QK^T: two independent 2-deep MFMA chains over D-halves
      __builtin_amdgcn_s_setprio(1);
      f32x16 sa = {}, sb = {};
      sa = __builtin_amdgcn_mfma_f32_32x32x16_bf16(kf[0], qf[0], sa, 0, 0, 0);
      sb = __builtin_amdgcn_mfma_f32_32x32x16_bf16(kf[1], qf[1], sb, 0, 0, 0);
      sa = __builtin_amdgcn_mfma_f32_32x32x16_bf16(kf[2], qf[2], sa, 0, 0, 0);
      sb = __builtin_amdgcn_mfma_f32_32x32x16_bf16(kf[3], qf[3], sb, 0, 0, 0);
      __builtin_amdgcn_s_setprio(0);

      // scores already in log2 domain (Q pre-scaled by 0.125*log2e in ca_rope)
      float tv[16];
#pragma unroll
      for (int r = 0; r < 16; ++r) tv[r] = sa[r] + sb[r];
      if (t == nt - 1) {  // diagonal tile is exactly the last tile
#pragma unroll
        for (int r = 0; r < 16; ++r) {
          int kvr = (r & 3) + 8 * (r >> 2) + 4 * hi;
          if (kvr > lo) tv[r] = -3.0e38f;
        }
      }
      // balanced max tree (fuses to v_max3)
      float mx[8];
#pragma unroll
      for (int r = 0; r < 8; ++r) mx[r] = fmaxf(tv[2 * r], tv[2 * r + 1]);
#pragma unroll
      for (int r = 0; r < 4; ++r) mx[r] = fmaxf(mx[2 * r], mx[2 * r + 1]);
      float pmax = fmaxf(fmaxf(mx[0], mx[1]), fmaxf(mx[2], mx[3]));
      pmax = xhalf_max(pmax);
      if (!__all(pmax - m <= 11.0f)) {  // defer-max (T13), log2 units
        float mn = fmaxf(m, pmax);
        float al = exp2f(m - mn);
        m = mn;
        lsum *= al;
#pragma unroll
        for (int r = 0; r < 16; ++r) { acc0[r] *= al; acc1[r] *= al; }
      }
      float p[16];
#pragma unroll
      for (int r = 0; r < 16; ++r) p[r] = exp2f(tv[r] - m);
      // balanced sum tree
      float sm[8];
#pragma unroll
      for (int r = 0; r < 8; ++r) sm[r] = p[2 * r] + p[2 * r + 1];
#pragma unroll
      for (int r = 0; r < 4; ++r) sm[r] = sm[2 * r] + sm[2 * r + 1];
      float ps = (sm[0] + sm[1]) + (sm[2] + sm[3]);
      lsum += xhalf_sum(ps);

      // pack P -> bf16 pairs; kv redistribution via 4 permlane32_swap
      uint32_t pk[8];
#pragma unroll
      for (int i = 0; i < 8; ++i) pk[i] = pkbf(p[2 * i], p[2 * i + 1]);
      pl32swap(pk[0], pk[2]);
      pl32swap(pk[1], pk[3]);
      pl32swap(pk[4], pk[6]);
      pl32swap(pk[5], pk[7]);
      uint4 xw{pk[0], pk[1], pk[2], pk[3]}, yw{pk[4], pk[5], pk[6], pk[7]};
      bf16x8 PB0 = __builtin_bit_cast(bf16x8, xw);
      bf16x8 PB1 = __builtin_bit_cast(bf16x8, yw);
      __builtin_amdgcn_s_setprio(1);
      acc0 = __builtin_amdgcn_mfma_f32_32x32x16_bf16(vf[0], PB0, acc0, 0, 0, 0);
      acc1 = __builtin_amdgcn_mfma_f32_32x32x16_bf16(vf[2], PB0, acc1, 0, 0, 0);
      acc0 = __builtin_amdgcn_mfma_f32_32x32x16_bf16(vf[1], PB1, acc0, 0, 0, 0);
      acc1 = __builtin_amdgcn_mfma_f32_32x32x16_bf16(vf[3], PB1, acc1, 0, 0, 0);
      __builtin_amdgcn_s_setprio(0);
    }

    // epilogue: O^T (d-major regs) -> LDS transpose -> coalesced row writes
    float rl = __builtin_amdgcn_rcpf(lsum);
#pragma unroll
    for (int dc = 0; dc < 2; ++dc) {
      f32x16 a = dc ? acc1 : acc0;
#pragma unroll
      for (int i = 0; i < 8; ++i) {
        uint32_t pkd = pkbf(a[2 * i] * rl, a[2 * i + 1] * rl);
        int d2 = (i & 1) + 4 * (i >> 1) + 2 * hi + dc * 16;
        els[lo][d2] = pkd;
      }
    }
    __syncthreads();
    unsigned short* yp = y + (size_t)b * Tx * Cx + h * Dx;
#pragma unroll
    for (int pp = 0; pp < 16; ++pp) {
      int qr = 2 * pp + hi;
      uint32_t val = els[qr][lo];
      *(uint32_t*)(yp + (size_t)(qbase + qr) * Cx + lo * 2) = val;
    }
    __syncthreads();  // els reused by next pass
  }
}

}  // namespace

extern "C" void kernel_launch(void* const* d_in, const int* in_sizes, int n_in,
                              void* d_out, int out_size, void* d_ws, size_t ws_size,
                              hipStream_t stream) {
  const float* x = (const float*)d_in[0];
  const float* Wq = (const float*)d_in[1];
  const float* bq = (const float*)d_in[2];
  const float* Wk = (const float*)d_in[3];
  const float* bk = (const float*)d_in[4];
  const float* Wv = (const float*)d_in[5];
  const float* bv = (const float*)d_in[6];
  const float* Wp = (const float*)d_in[7];
  const float* bp = (const float*)d_in[8];

  unsigned short* xb = (unsigned short*)d_ws;                 // 8192*1024
  unsigned short* wt = xb + (size_t)Mx * Cx;                  // 4 * 1024*1024 (WqT,WkT,WvT,WpT)
  float* ct = (float*)(wt + (size_t)4 * Cx * Cx);             // 2048*32
  float* st = ct + Tx * 32;
  unsigned short* qb = (unsigned short*)(st + Tx * 32);       // q,k,v consecutive (split3 GEMM out)
  unsigned short* kb = qb + (size_t)Mx * Cx;
  unsigned short* vb = kb + (size_t)Mx * Cx;
  unsigned short* vT = vb + (size_t)Mx * Cx;
  unsigned short* yb = vT + (size_t)Mx * Cx;

  ca_cvt<<<dim3(2048), dim3(256), 0, stream>>>(x, xb, Mx * Cx / 4);
  ca_wt<<<dim3(32, 32), dim3(256), 0, stream>>>(Wq, wt + (size_t)0 * Cx * Cx);
  ca_wt<<<dim3(32, 32), dim3(256), 0, stream>>>(Wk, wt + (size_t)1 * Cx * Cx);
  ca_wt<<<dim3(32, 32), dim3(256), 0, stream>>>(Wv, wt + (size_t)2 * Cx * Cx);
  ca_wt<<<dim3(32, 32), dim3(256), 0, stream>>>(Wp, wt + (size_t)3 * Cx * Cx);
  ca_rtab<<<dim3(Tx * 32 / 256), dim3(256), 0, stream>>>(ct, st);

  ca_gemm<0><<<dim3(64, 24), dim3(256), 0, stream>>>(xb, wt, bq, bk, bv, qb, Mx, 3072, Cx);
  ca_rope<<<dim3(Mx * Cx / 8 / 256), dim3(256), 0, stream>>>(qb, kb, ct, st);
  ca_vt<<<dim3(Tx / 64, Bx * Hx), dim3(256), 0, stream>>>(vb, vT);
  ca_attn<<<dim3(64, 32), dim3(64), 0, stream>>>(qb, kb, vT, yb);
  ca_gemm<1><<<dim3(64, 8), dim3(256), 0, stream>>>(yb, wt + (size_t)3 * Cx * Cx, bp,
                                                    nullptr, nullptr, d_out, Mx, Cx, Cx);
}